// Round 2
// baseline (881.735 us; speedup 1.0000x reference)
//
#include <hip/hip_runtime.h>
#include <hip/hip_bf16.h>

#define NB 32
#define NP 2048
#define NS 64
#define NK 128

// d_out layout (FLOAT32 elements)
#define MEAN_OFF 0
#define STD_OFF  1048576
#define XIDX_OFF 2097152
#define YIDX_OFF 2359296

static __device__ __forceinline__ float leaky(float x){ return x >= 0.0f ? x : 0.2f * x; }

// strict IEEE fp32, no contraction: ((dx*dx + dy*dy) + dz*dz) — matches numpy/jax op order
static __device__ __forceinline__ float d2s(float ax,float ay,float az,float bx,float by,float bz){
    float dx = __fsub_rn(ax,bx), dy = __fsub_rn(ay,by), dz = __fsub_rn(az,bz);
    return __fadd_rn(__fadd_rn(__fmul_rn(dx,dx),__fmul_rn(dy,dy)),__fmul_rn(dz,dz));
}

// ---------------- FPS: one block per batch ----------------
__global__ __launch_bounds__(256) void fps_kernel(const float* __restrict__ pos,
                                                  float* __restrict__ centersWs)
{
    int b = blockIdx.x;
    int t = threadIdx.x;
    __shared__ float px[NP], py[NP], pz[NP];
    __shared__ float redv[4];
    __shared__ int   redi[4];
    __shared__ int   jsh;

    const float* pb = pos + (size_t)b * NP * 3;
    for (int n = t; n < NP; n += 256) {
        px[n] = pb[n*3+0]; py[n] = pb[n*3+1]; pz[n] = pb[n*3+2];
    }
    __syncthreads();

    float p0x = px[0], p0y = py[0], p0z = pz[0];
    float dl[8];
    #pragma unroll
    for (int q = 0; q < 8; q++) {
        int n = t + q*256;
        dl[q] = d2s(px[n],py[n],pz[n], p0x,p0y,p0z);
    }
    if (t == 0) {
        centersWs[(b*NS)*3+0] = p0x;
        centersWs[(b*NS)*3+1] = p0y;
        centersWs[(b*NS)*3+2] = p0z;
    }

    for (int s = 1; s < NS; s++) {
        // local argmax (first index wins ties: ascending n + strict >)
        float bv = -1.0f; int bi = 0;
        #pragma unroll
        for (int q = 0; q < 8; q++) {
            int n = t + q*256;
            if (dl[q] > bv) { bv = dl[q]; bi = n; }
        }
        // wave butterfly reduce, min-index on equal
        #pragma unroll
        for (int m = 32; m > 0; m >>= 1) {
            float ov = __shfl_xor(bv, m);
            int   oi = __shfl_xor(bi, m);
            if (ov > bv || (ov == bv && oi < bi)) { bv = ov; bi = oi; }
        }
        int w = t >> 6;
        if ((t & 63) == 0) { redv[w] = bv; redi[w] = bi; }
        __syncthreads();
        if (t == 0) {
            float v = redv[0]; int i = redi[0];
            #pragma unroll
            for (int k = 1; k < 4; k++) {
                if (redv[k] > v || (redv[k] == v && redi[k] < i)) { v = redv[k]; i = redi[k]; }
            }
            jsh = i;
            centersWs[(b*NS+s)*3+0] = px[i];
            centersWs[(b*NS+s)*3+1] = py[i];
            centersWs[(b*NS+s)*3+2] = pz[i];
        }
        __syncthreads();
        int j = jsh;
        float cx = px[j], cy = py[j], cz = pz[j];
        #pragma unroll
        for (int q = 0; q < 8; q++) {
            int n = t + q*256;
            dl[q] = fminf(dl[q], d2s(px[n],py[n],pz[n], cx,cy,cz));
        }
    }
}

// ---------------- ball query: one wave per center ----------------
__global__ __launch_bounds__(64) void ball_kernel(const float* __restrict__ pos,
                                                  const float* __restrict__ centersWs,
                                                  int* __restrict__ nbrWs,
                                                  int* __restrict__ cntWs,
                                                  float* __restrict__ gA,
                                                  float* __restrict__ out)
{
    int r = blockIdx.x;        // b*NS + s
    int b = r >> 6;
    int lane = threadIdx.x;
    float cx = centersWs[r*3+0], cy = centersWs[r*3+1], cz = centersWs[r*3+2];

    __shared__ int nb[NK];
    const float* pb = pos + (size_t)b * NP * 3;
    int total = 0;
    for (int base = 0; base < NP; base += 64) {
        int n = base + lane;
        float x = pb[n*3+0], y = pb[n*3+1], z = pb[n*3+2];
        float d2 = d2s(cx,cy,cz, x,y,z);
        bool in = d2 < 0.04f;
        unsigned long long m = __ballot(in);
        int before = __popcll(m & ((1ull << lane) - 1ull));
        int p = total + before;
        if (in && p < NK) nb[p] = n;
        total += (int)__popcll(m);
        if (total >= NK) break;
    }
    int cnt = total > NK ? NK : total;
    if (lane == 0) cntWs[r] = cnt;
    __syncthreads();

    #pragma unroll
    for (int k = lane; k < NK; k += 64) {
        bool valid = k < cnt;
        int nv = valid ? nb[k] : 0;
        nbrWs[r*NK + k] = nv;
        out[XIDX_OFF + r*NK + k] = valid ? (float)(nv + b*NP) : -1.0f;
        out[YIDX_OFF + r*NK + k] = valid ? (float)r : -1.0f;
    }
    // gA tail: cols 512..514 = center, 515..527 = 0
    if (lane < 16) {
        float v = 0.0f;
        if (lane == 0) v = cx; else if (lane == 1) v = cy; else if (lane == 2) v = cz;
        gA[(size_t)r*528 + 512 + lane] = v;
    }
}

// ---------------- fused MLP(3->64->128->512) + masked max over K ----------------
__global__ __launch_bounds__(512) void mlp_kernel(const float* __restrict__ pos,
                                                  const float* __restrict__ W1, const float* __restrict__ b1,
                                                  const float* __restrict__ W2, const float* __restrict__ b2,
                                                  const float* __restrict__ W3, const float* __restrict__ b3,
                                                  const float* __restrict__ centersWs,
                                                  const int* __restrict__ nbrWs,
                                                  const int* __restrict__ cntWs,
                                                  float* __restrict__ gA)
{
    __shared__ float smem[32768];                 // 128 KB
    float* h2T = smem;                            // [128][128]  [0,16384)
    float* rel = smem;                            // alias, first 512 floats (dead before h2T written)
    float* h1T = smem + 16384;                    // [64][128]
    float* w2s = smem + 24576;                    // [64][128]
    float* w3s = smem + 16384;                    // layer3 alias of h1T: [128][64]
    float* red = smem + 24576;                    // layer3 alias of w2s: [32][64]

    int r = blockIdx.x, b = r >> 6, tid = threadIdx.x;
    int cnt = cntWs[r];
    float cx = centersWs[r*3+0], cy = centersWs[r*3+1], cz = centersWs[r*3+2];

    if (tid < NK) {
        int nv = nbrWs[r*NK + tid];
        const float* pp = pos + ((size_t)b*NP + nv)*3;
        rel[tid*4+0] = pp[0] - cx;
        rel[tid*4+1] = pp[1] - cy;
        rel[tid*4+2] = pp[2] - cz;
        rel[tid*4+3] = 0.0f;
    }
    {
        const float4* src = (const float4*)W2;
        float4* dst = (float4*)w2s;
        for (int e = tid; e < 2048; e += 512) dst[e] = src[e];
    }
    __syncthreads();

    // layer 1: h1T[j][k] = leaky(rel[k]·W1[:,j] + b1[j])
    {
        int j = tid & 63;
        int kb = (tid >> 6) << 4;
        float wa = W1[j], wb = W1[64+j], wc = W1[128+j], bb = b1[j];
        #pragma unroll
        for (int k = kb; k < kb+16; k++) {
            float a = bb + rel[k*4+0]*wa + rel[k*4+1]*wb + rel[k*4+2]*wc;
            h1T[j*NK + k] = leaky(a);
        }
    }
    __syncthreads();

    // layer 2: h2T[i][k] = leaky(sum_j h1T[j][k]*W2[j][i] + b2[i])
    {
        int ti = tid >> 5, tk = tid & 31;
        int k0 = tk*4;
        #pragma unroll
        for (int pass = 0; pass < 2; pass++) {
            int i0 = pass*64 + ti*4;
            float acc[4][4];
            #pragma unroll
            for (int q = 0; q < 4; q++)
                #pragma unroll
                for (int kk = 0; kk < 4; kk++) acc[q][kk] = 0.0f;
            for (int j = 0; j < 64; j++) {
                float4 wv = *(const float4*)&w2s[j*NK + i0];
                float4 hv = *(const float4*)&h1T[j*NK + k0];
                float wq[4] = {wv.x, wv.y, wv.z, wv.w};
                float hq[4] = {hv.x, hv.y, hv.z, hv.w};
                #pragma unroll
                for (int q = 0; q < 4; q++)
                    #pragma unroll
                    for (int kk = 0; kk < 4; kk++) acc[q][kk] += wq[q]*hq[kk];
            }
            #pragma unroll
            for (int q = 0; q < 4; q++) {
                float bb = b2[i0+q];
                float4 o;
                o.x = leaky(acc[q][0]+bb); o.y = leaky(acc[q][1]+bb);
                o.z = leaky(acc[q][2]+bb); o.w = leaky(acc[q][3]+bb);
                *(float4*)&h2T[(i0+q)*NK + k0] = o;
            }
        }
    }
    __syncthreads();

    // layer 3: feat[c] = leaky(max_{k<cnt} sum_i h2T[i][k]*W3[i][c] + b3[c])
    {
        int tc = tid & 15, tk3 = tid >> 4;
        int cl0 = tc*4, k0 = tk3*4;
        for (int c0 = 0; c0 < 512; c0 += 64) {
            {
                float4* dst = (float4*)w3s;
                for (int e = tid; e < 2048; e += 512) {
                    int i = e >> 4, cl = (e & 15) << 2;
                    dst[e] = *(const float4*)&W3[i*512 + c0 + cl];
                }
            }
            __syncthreads();
            float acc[4][4];   // [kk][q]
            #pragma unroll
            for (int kk = 0; kk < 4; kk++)
                #pragma unroll
                for (int q = 0; q < 4; q++) acc[kk][q] = 0.0f;
            for (int i = 0; i < NK; i++) {
                float4 hv = *(const float4*)&h2T[i*NK + k0];
                float4 wv = *(const float4*)&w3s[i*64 + cl0];
                float hq[4] = {hv.x, hv.y, hv.z, hv.w};
                float wq[4] = {wv.x, wv.y, wv.z, wv.w};
                #pragma unroll
                for (int kk = 0; kk < 4; kk++)
                    #pragma unroll
                    for (int q = 0; q < 4; q++) acc[kk][q] += hq[kk]*wq[q];
            }
            #pragma unroll
            for (int q = 0; q < 4; q++) {
                float m = -INFINITY;
                #pragma unroll
                for (int kk = 0; kk < 4; kk++)
                    if (k0 + kk < cnt) m = fmaxf(m, acc[kk][q]);
                red[tk3*64 + cl0 + q] = m;
            }
            __syncthreads();
            if (tid < 64) {
                float v = red[tid];
                #pragma unroll 4
                for (int tt = 1; tt < 32; tt++) v = fmaxf(v, red[tt*64 + tid]);
                int c = c0 + tid;
                gA[(size_t)r*528 + c] = leaky(v + b3[c]);
            }
            __syncthreads();
        }
    }
}

// ---------------- FC1: g2 = leaky(gA[2048,528(515)] @ W4[515,512] + b4) ----------------
__global__ __launch_bounds__(256) void fc1_kernel(const float* __restrict__ gA,
                                                  const float* __restrict__ W4,
                                                  const float* __restrict__ b4,
                                                  float* __restrict__ g2)
{
    int bx = blockIdx.x & 7;      // col tile (512/64)
    int by = blockIdx.x >> 3;     // row tile (2048/64)
    __shared__ float AsT[16*64];  // [k][row]
    __shared__ float Bs[16*64];   // [k][col]
    int tid = threadIdx.x;
    int tx = tid & 15, ty = tid >> 4;
    int row0 = by*64 + ty*4, col0 = bx*64 + tx*4;
    float acc[4][4];
    #pragma unroll
    for (int a = 0; a < 4; a++)
        #pragma unroll
        for (int c = 0; c < 4; c++) acc[a][c] = 0.0f;

    for (int kb = 0; kb < 528; kb += 16) {
        for (int e = tid; e < 1024; e += 256) {
            int k = e & 15, rr = e >> 4;
            AsT[k*64 + rr] = gA[(size_t)(by*64 + rr)*528 + kb + k];
        }
        for (int e = tid; e < 1024; e += 256) {
            int cc = e & 63, k = e >> 6;
            int kg = kb + k;
            Bs[k*64 + cc] = (kg < 515) ? W4[(size_t)kg*512 + bx*64 + cc] : 0.0f;
        }
        __syncthreads();
        #pragma unroll
        for (int k = 0; k < 16; k++) {
            float4 av = *(const float4*)&AsT[k*64 + ty*4];
            float4 bv = *(const float4*)&Bs[k*64 + tx*4];
            float aq[4] = {av.x, av.y, av.z, av.w};
            float bq[4] = {bv.x, bv.y, bv.z, bv.w};
            #pragma unroll
            for (int a = 0; a < 4; a++)
                #pragma unroll
                for (int c = 0; c < 4; c++) acc[a][c] += aq[a]*bq[c];
        }
        __syncthreads();
    }
    #pragma unroll
    for (int a = 0; a < 4; a++) {
        float4 o;
        o.x = leaky(acc[a][0] + b4[col0+0]);
        o.y = leaky(acc[a][1] + b4[col0+1]);
        o.z = leaky(acc[a][2] + b4[col0+2]);
        o.w = leaky(acc[a][3] + b4[col0+3]);
        *(float4*)&g2[(size_t)(row0+a)*512 + col0] = o;
    }
}

// ---------------- FC2: out = g2 @ W5[512,1024] + b5; mean | std=exp(0.5 logvar) ----------------
__global__ __launch_bounds__(256) void fc2_kernel(const float* __restrict__ g2,
                                                  const float* __restrict__ W5,
                                                  const float* __restrict__ b5,
                                                  float* __restrict__ out)
{
    int bx = blockIdx.x & 15;     // col tile (1024/64)
    int by = blockIdx.x >> 4;     // row tile (2048/64)
    __shared__ float AsT[16*64];
    __shared__ float Bs[16*64];
    int tid = threadIdx.x;
    int tx = tid & 15, ty = tid >> 4;
    int row0 = by*64 + ty*4, col0 = bx*64 + tx*4;
    float acc[4][4];
    #pragma unroll
    for (int a = 0; a < 4; a++)
        #pragma unroll
        for (int c = 0; c < 4; c++) acc[a][c] = 0.0f;

    for (int kb = 0; kb < 512; kb += 16) {
        for (int e = tid; e < 1024; e += 256) {
            int k = e & 15, rr = e >> 4;
            AsT[k*64 + rr] = g2[(size_t)(by*64 + rr)*512 + kb + k];
        }
        for (int e = tid; e < 1024; e += 256) {
            int cc = e & 63, k = e >> 6;
            Bs[k*64 + cc] = W5[(size_t)(kb + k)*1024 + bx*64 + cc];
        }
        __syncthreads();
        #pragma unroll
        for (int k = 0; k < 16; k++) {
            float4 av = *(const float4*)&AsT[k*64 + ty*4];
            float4 bv = *(const float4*)&Bs[k*64 + tx*4];
            float aq[4] = {av.x, av.y, av.z, av.w};
            float bq[4] = {bv.x, bv.y, bv.z, bv.w};
            #pragma unroll
            for (int a = 0; a < 4; a++)
                #pragma unroll
                for (int c = 0; c < 4; c++) acc[a][c] += aq[a]*bq[c];
        }
        __syncthreads();
    }
    #pragma unroll
    for (int a = 0; a < 4; a++) {
        int row = row0 + a;
        #pragma unroll
        for (int c = 0; c < 4; c++) {
            int col = col0 + c;
            float v = acc[a][c] + b5[col];
            if (col < 512) {
                out[MEAN_OFF + (size_t)row*512 + col] = v;
            } else {
                out[STD_OFF + (size_t)row*512 + (col - 512)] = expf(0.5f*v);
            }
        }
    }
}

extern "C" void kernel_launch(void* const* d_in, const int* in_sizes, int n_in,
                              void* d_out, int out_size, void* d_ws, size_t ws_size,
                              hipStream_t stream) {
    const float* pos = (const float*)d_in[0];
    const float* W1  = (const float*)d_in[2];
    const float* b1  = (const float*)d_in[3];
    const float* W2  = (const float*)d_in[4];
    const float* b2  = (const float*)d_in[5];
    const float* W3  = (const float*)d_in[6];
    const float* b3  = (const float*)d_in[7];
    const float* W4  = (const float*)d_in[8];
    const float* b4  = (const float*)d_in[9];
    const float* W5  = (const float*)d_in[10];
    const float* b5  = (const float*)d_in[11];
    float* out = (float*)d_out;

    char* ws = (char*)d_ws;
    float* centersWs = (float*)(ws);             // 2048*3 f32          [0, 24576)
    int*   cntWs     = (int*)(ws + 24576);       // 2048 i32            [24576, 32768)
    int*   nbrWs     = (int*)(ws + 32768);       // 2048*128 i32        [32768, 1081344)
    float* gA        = (float*)(ws + 1081344);   // 2048*528 f32        [1081344, 5406720)
    float* g2        = (float*)(ws + 5406720);   // 2048*512 f32        [5406720, 9601024)

    hipLaunchKernelGGL(fps_kernel, dim3(NB), dim3(256), 0, stream, pos, centersWs);
    hipLaunchKernelGGL(ball_kernel, dim3(NB*NS), dim3(64), 0, stream, pos, centersWs, nbrWs, cntWs, gA, out);
    hipLaunchKernelGGL(mlp_kernel, dim3(NB*NS), dim3(512), 0, stream,
                       pos, W1,b1, W2,b2, W3,b3, centersWs, nbrWs, cntWs, gA);
    hipLaunchKernelGGL(fc1_kernel, dim3(256), dim3(256), 0, stream, gA, W4, b4, g2);
    hipLaunchKernelGGL(fc2_kernel, dim3(512), dim3(256), 0, stream, g2, W5, b5, out);
}

// Round 3
// 335.147 us; speedup vs baseline: 2.6309x; 2.6309x over previous
//
#include <hip/hip_runtime.h>
#include <hip/hip_bf16.h>

#define NB 32
#define NP 2048
#define NS 64
#define NK 128

// d_out layout (FLOAT32 elements)
#define MEAN_OFF 0
#define STD_OFF  1048576
#define XIDX_OFF 2097152
#define YIDX_OFF 2359296

typedef __attribute__((ext_vector_type(8)))  short short8;
typedef __attribute__((ext_vector_type(16))) float f32x16;

static __device__ __forceinline__ float leaky(float x){ return x >= 0.0f ? x : 0.2f * x; }

// strict IEEE fp32, no contraction — matches numpy/jax op order
static __device__ __forceinline__ float d2s(float ax,float ay,float az,float bx,float by,float bz){
    float dx = __fsub_rn(ax,bx), dy = __fsub_rn(ay,by), dz = __fsub_rn(az,bz);
    return __fadd_rn(__fadd_rn(__fmul_rn(dx,dx),__fmul_rn(dy,dy)),__fmul_rn(dz,dz));
}

// ---------------- FPS: one block per batch ----------------
__global__ __launch_bounds__(256) void fps_kernel(const float* __restrict__ pos,
                                                  float* __restrict__ centersWs)
{
    int b = blockIdx.x;
    int t = threadIdx.x;
    __shared__ float px[NP], py[NP], pz[NP];
    __shared__ float redv[4];
    __shared__ int   redi[4];
    __shared__ int   jsh;

    const float* pb = pos + (size_t)b * NP * 3;
    for (int n = t; n < NP; n += 256) {
        px[n] = pb[n*3+0]; py[n] = pb[n*3+1]; pz[n] = pb[n*3+2];
    }
    __syncthreads();

    float p0x = px[0], p0y = py[0], p0z = pz[0];
    float dl[8];
    #pragma unroll
    for (int q = 0; q < 8; q++) {
        int n = t + q*256;
        dl[q] = d2s(px[n],py[n],pz[n], p0x,p0y,p0z);
    }
    if (t == 0) {
        centersWs[(b*NS)*3+0] = p0x;
        centersWs[(b*NS)*3+1] = p0y;
        centersWs[(b*NS)*3+2] = p0z;
    }

    for (int s = 1; s < NS; s++) {
        float bv = -1.0f; int bi = 0;
        #pragma unroll
        for (int q = 0; q < 8; q++) {
            int n = t + q*256;
            if (dl[q] > bv) { bv = dl[q]; bi = n; }
        }
        #pragma unroll
        for (int m = 32; m > 0; m >>= 1) {
            float ov = __shfl_xor(bv, m);
            int   oi = __shfl_xor(bi, m);
            if (ov > bv || (ov == bv && oi < bi)) { bv = ov; bi = oi; }
        }
        int w = t >> 6;
        if ((t & 63) == 0) { redv[w] = bv; redi[w] = bi; }
        __syncthreads();
        if (t == 0) {
            float v = redv[0]; int i = redi[0];
            #pragma unroll
            for (int k = 1; k < 4; k++) {
                if (redv[k] > v || (redv[k] == v && redi[k] < i)) { v = redv[k]; i = redi[k]; }
            }
            jsh = i;
            centersWs[(b*NS+s)*3+0] = px[i];
            centersWs[(b*NS+s)*3+1] = py[i];
            centersWs[(b*NS+s)*3+2] = pz[i];
        }
        __syncthreads();
        int j = jsh;
        float cx = px[j], cy = py[j], cz = pz[j];
        #pragma unroll
        for (int q = 0; q < 8; q++) {
            int n = t + q*256;
            dl[q] = fminf(dl[q], d2s(px[n],py[n],pz[n], cx,cy,cz));
        }
    }
}

// ---------------- ball query: one wave per center ----------------
__global__ __launch_bounds__(64) void ball_kernel(const float* __restrict__ pos,
                                                  const float* __restrict__ centersWs,
                                                  int* __restrict__ nbrWs,
                                                  int* __restrict__ cntWs,
                                                  float* __restrict__ gA,
                                                  float* __restrict__ out)
{
    int r = blockIdx.x;        // b*NS + s
    int b = r >> 6;
    int lane = threadIdx.x;
    float cx = centersWs[r*3+0], cy = centersWs[r*3+1], cz = centersWs[r*3+2];

    __shared__ int nb[NK];
    const float* pb = pos + (size_t)b * NP * 3;
    int total = 0;
    for (int base = 0; base < NP; base += 64) {
        int n = base + lane;
        float x = pb[n*3+0], y = pb[n*3+1], z = pb[n*3+2];
        float d2 = d2s(cx,cy,cz, x,y,z);
        bool in = d2 < 0.04f;
        unsigned long long m = __ballot(in);
        int before = __popcll(m & ((1ull << lane) - 1ull));
        int p = total + before;
        if (in && p < NK) nb[p] = n;
        total += (int)__popcll(m);
        if (total >= NK) break;
    }
    int cnt = total > NK ? NK : total;
    if (lane == 0) cntWs[r] = cnt;
    __syncthreads();

    #pragma unroll
    for (int k = lane; k < NK; k += 64) {
        bool valid = k < cnt;
        int nv = valid ? nb[k] : 0;
        nbrWs[r*NK + k] = nv;
        out[XIDX_OFF + r*NK + k] = valid ? (float)(nv + b*NP) : -1.0f;
        out[YIDX_OFF + r*NK + k] = valid ? (float)r : -1.0f;
    }
    if (lane < 16) {
        float v = 0.0f;
        if (lane == 0) v = cx; else if (lane == 1) v = cy; else if (lane == 2) v = cz;
        gA[(size_t)r*528 + 512 + lane] = v;
    }
}

// ---------------- prep: bf16 transposed+swizzled weights into ws ----------------
// W2T: [i=0..127][j=0..63] bf16, byte = i*128 + ((j*2) ^ ((i&7)<<4))    (16 KB)
// W3T: [c=0..511][i=0..127] bf16, byte = c*256 + ((i*2) ^ ((c&15)<<4)) (128 KB)
__global__ __launch_bounds__(256) void prep_kernel(const float* __restrict__ W2,
                                                   const float* __restrict__ W3,
                                                   __hip_bfloat16* __restrict__ W2T,
                                                   __hip_bfloat16* __restrict__ W3T)
{
    int g = blockIdx.x*256 + threadIdx.x;   // 0..65535
    {
        int c = g & 511, i = g >> 9;
        float v = W3[(size_t)i*512 + c];
        int byte = c*256 + ((i*2) ^ ((c&15)<<4));
        W3T[byte>>1] = __float2bfloat16(v);
    }
    if (g < 8192) {
        int j = g >> 7, i = g & 127;
        float v = W2[(size_t)j*128 + i];
        int byte = i*128 + ((j*2) ^ ((i&7)<<4));
        W2T[byte>>1] = __float2bfloat16(v);
    }
}

// ---------------- fused MLP(3->64->128->512) + masked max, MFMA bf16 ----------------
__global__ __launch_bounds__(256) void mlp_kernel(const float* __restrict__ pos,
                                                  const float* __restrict__ W1, const float* __restrict__ b1,
                                                  const float* __restrict__ b2, const float* __restrict__ b3,
                                                  const __hip_bfloat16* __restrict__ W2T,
                                                  const __hip_bfloat16* __restrict__ W3T,
                                                  const float* __restrict__ centersWs,
                                                  const int* __restrict__ nbrWs,
                                                  const int* __restrict__ cntWs,
                                                  float* __restrict__ gA)
{
    __shared__ char smem[67584];
    char* h1s = smem;                 // [0,16384)       layer1 out  [k][j] swz (k&7)<<4
    char* w2s = smem + 16384;         // [16384,32768)   W2T image
    char* w3s = smem;                 // [0,32768)       layer3 B chunk (aliases h1s+w2s)
    char* h2s = smem + 32768;         // [32768,65536)   layer2 out  [k][i] swz (k&15)<<4
    float* rel = (float*)(smem + 65536);   // 128*4 f32 (2 KB)
    float* red = (float*)(smem + 65536);   // 256 f32 (aliases rel; rel dead by layer3)

    int r = blockIdx.x, b = r >> 6, tid = threadIdx.x;
    int l = tid & 63, w = tid >> 6;
    int wr = w & 1, wc = w >> 1;
    int colsel = (l >> 5) * 16;       // byte offset of the lane's K-subgroup
    int cnt = cntWs[r];
    float cx = centersWs[r*3+0], cy = centersWs[r*3+1], cz = centersWs[r*3+2];

    // stage W2T -> LDS (linear copy; swizzle pre-applied by prep)
    #pragma unroll
    for (int it = 0; it < 4; it++) {
        int off = (it*256 + tid) * 16;
        *(short8*)(w2s + off) = *(const short8*)((const char*)W2T + off);
    }
    if (tid < NK) {
        int nv = nbrWs[r*NK + tid];
        const float* pp = pos + ((size_t)b*NP + nv)*3;
        rel[tid*4+0] = pp[0] - cx;
        rel[tid*4+1] = pp[1] - cy;
        rel[tid*4+2] = pp[2] - cz;
        rel[tid*4+3] = 0.0f;
    }
    __syncthreads();

    // ---- layer 1 (VALU): h1[k][j] = leaky(rel[k]·W1[:,j] + b1[j]) -> bf16 LDS
    {
        int j = l;
        float wa = W1[j], wb = W1[64+j], wcc = W1[128+j], bb = b1[j];
        #pragma unroll
        for (int e = 0; e < 32; e++) {
            int k = e*4 + w;
            float a = bb + rel[k*4+0]*wa + rel[k*4+1]*wb + rel[k*4+2]*wcc;
            a = leaky(a);
            int byte = k*128 + ((j*2) ^ ((k&7)<<4));
            *(__hip_bfloat16*)(h1s + byte) = __float2bfloat16(a);
        }
    }
    __syncthreads();

    // ---- layer 2 (MFMA): h2[k][i] = leaky(h1 @ W2 + b2), M=128,N=128,K=64
    {
        f32x16 acc[2][2];
        #pragma unroll
        for (int q = 0; q < 16; q++) { acc[0][0][q]=0.f; acc[0][1][q]=0.f; acc[1][0][q]=0.f; acc[1][1][q]=0.f; }
        int ra0 = (2*wr)*32 + (l & 31), ra1 = ra0 + 32;   // A rows (k)
        int rb0 = (2*wc)*32 + (l & 31), rb1 = rb0 + 32;   // B rows (i) in W2T
        #pragma unroll
        for (int ks = 0; ks < 4; ks++) {
            int bc = ks*32 + colsel;
            short8 a0 = *(short8*)(h1s + ra0*128 + (bc ^ ((ra0&7)<<4)));
            short8 a1 = *(short8*)(h1s + ra1*128 + (bc ^ ((ra1&7)<<4)));
            short8 bv0 = *(short8*)(w2s + rb0*128 + (bc ^ ((rb0&7)<<4)));
            short8 bv1 = *(short8*)(w2s + rb1*128 + (bc ^ ((rb1&7)<<4)));
            acc[0][0] = __builtin_amdgcn_mfma_f32_32x32x16_bf16(a0, bv0, acc[0][0], 0, 0, 0);
            acc[0][1] = __builtin_amdgcn_mfma_f32_32x32x16_bf16(a0, bv1, acc[0][1], 0, 0, 0);
            acc[1][0] = __builtin_amdgcn_mfma_f32_32x32x16_bf16(a1, bv0, acc[1][0], 0, 0, 0);
            acc[1][1] = __builtin_amdgcn_mfma_f32_32x32x16_bf16(a1, bv1, acc[1][1], 0, 0, 0);
        }
        float bi0 = b2[rb0], bi1 = b2[rb1];
        #pragma unroll
        for (int rt = 0; rt < 2; rt++) {
            int kbase = (2*wr + rt)*32 + 4*(l>>5);
            #pragma unroll
            for (int reg = 0; reg < 16; reg++) {
                int k = kbase + (reg&3) + 8*(reg>>2);
                float v0 = leaky(acc[rt][0][reg] + bi0);
                float v1 = leaky(acc[rt][1][reg] + bi1);
                *(__hip_bfloat16*)(h2s + k*256 + ((rb0*2) ^ ((k&15)<<4))) = __float2bfloat16(v0);
                *(__hip_bfloat16*)(h2s + k*256 + ((rb1*2) ^ ((k&15)<<4))) = __float2bfloat16(v1);
            }
        }
    }
    __syncthreads();

    // ---- preload layer3 A-frags (h2) into registers: reused across all 4 chunks
    short8 a3[2][8];
    {
        #pragma unroll
        for (int rt = 0; rt < 2; rt++) {
            int row = (2*wr + rt)*32 + (l & 31);
            #pragma unroll
            for (int ks = 0; ks < 8; ks++) {
                int bc = ks*32 + colsel;
                a3[rt][ks] = *(short8*)(h2s + row*256 + (bc ^ ((row&15)<<4)));
            }
        }
    }

    // ---- layer 3 (MFMA) + masked max: N=512 in 4 chunks of 128 cols
    int rb0 = (2*wc)*32 + (l & 31), rb1 = rb0 + 32;       // B rows (c_local) in W3T chunk
    for (int cc = 0; cc < 4; cc++) {
        const char* src = (const char*)W3T + cc*32768;
        #pragma unroll
        for (int it = 0; it < 8; it++) {
            int off = (it*256 + tid) * 16;
            *(short8*)(w3s + off) = *(const short8*)(src + off);
        }
        __syncthreads();

        f32x16 a00, a01, a10, a11;
        #pragma unroll
        for (int q = 0; q < 16; q++) { a00[q]=0.f; a01[q]=0.f; a10[q]=0.f; a11[q]=0.f; }
        #pragma unroll
        for (int ks = 0; ks < 8; ks++) {
            int bc = ks*32 + colsel;
            short8 bv0 = *(short8*)(w3s + rb0*256 + (bc ^ ((rb0&15)<<4)));
            short8 bv1 = *(short8*)(w3s + rb1*256 + (bc ^ ((rb1&15)<<4)));
            a00 = __builtin_amdgcn_mfma_f32_32x32x16_bf16(a3[0][ks], bv0, a00, 0, 0, 0);
            a01 = __builtin_amdgcn_mfma_f32_32x32x16_bf16(a3[0][ks], bv1, a01, 0, 0, 0);
            a10 = __builtin_amdgcn_mfma_f32_32x32x16_bf16(a3[1][ks], bv0, a10, 0, 0, 0);
            a11 = __builtin_amdgcn_mfma_f32_32x32x16_bf16(a3[1][ks], bv1, a11, 0, 0, 0);
        }
        // masked max over this wave's 64 k-rows
        float m0 = -INFINITY, m1 = -INFINITY;
        int kb0 = 2*wr*32 + 4*(l>>5);
        #pragma unroll
        for (int reg = 0; reg < 16; reg++) {
            int kloc = (reg&3) + 8*(reg>>2);
            if (kb0 + kloc < cnt)      { m0 = fmaxf(m0, a00[reg]); m1 = fmaxf(m1, a01[reg]); }
            if (kb0 + 32 + kloc < cnt) { m0 = fmaxf(m0, a10[reg]); m1 = fmaxf(m1, a11[reg]); }
        }
        m0 = fmaxf(m0, __shfl_xor(m0, 32));
        m1 = fmaxf(m1, __shfl_xor(m1, 32));
        if (l < 32) {
            red[wr*128 + rb0] = m0;
            red[wr*128 + rb1] = m1;
        }
        __syncthreads();
        if (tid < 128) {
            float m = fmaxf(red[tid], red[128 + tid]);
            int c = cc*128 + tid;
            gA[(size_t)r*528 + c] = leaky(m + b3[c]);
        }
        __syncthreads();
    }
}

// ---------------- FC1: g2 = leaky(gA[2048,528(515)] @ W4[515,512] + b4) ----------------
__global__ __launch_bounds__(256) void fc1_kernel(const float* __restrict__ gA,
                                                  const float* __restrict__ W4,
                                                  const float* __restrict__ b4,
                                                  float* __restrict__ g2)
{
    int bx = blockIdx.x & 7;
    int by = blockIdx.x >> 3;
    __shared__ float AsT[16*64];
    __shared__ float Bs[16*64];
    int tid = threadIdx.x;
    int tx = tid & 15, ty = tid >> 4;
    int row0 = by*64 + ty*4, col0 = bx*64 + tx*4;
    float acc[4][4];
    #pragma unroll
    for (int a = 0; a < 4; a++)
        #pragma unroll
        for (int c = 0; c < 4; c++) acc[a][c] = 0.0f;

    for (int kb = 0; kb < 528; kb += 16) {
        for (int e = tid; e < 1024; e += 256) {
            int k = e & 15, rr = e >> 4;
            AsT[k*64 + rr] = gA[(size_t)(by*64 + rr)*528 + kb + k];
        }
        for (int e = tid; e < 1024; e += 256) {
            int cc = e & 63, k = e >> 6;
            int kg = kb + k;
            Bs[k*64 + cc] = (kg < 515) ? W4[(size_t)kg*512 + bx*64 + cc] : 0.0f;
        }
        __syncthreads();
        #pragma unroll
        for (int k = 0; k < 16; k++) {
            float4 av = *(const float4*)&AsT[k*64 + ty*4];
            float4 bv = *(const float4*)&Bs[k*64 + tx*4];
            float aq[4] = {av.x, av.y, av.z, av.w};
            float bq[4] = {bv.x, bv.y, bv.z, bv.w};
            #pragma unroll
            for (int a = 0; a < 4; a++)
                #pragma unroll
                for (int c = 0; c < 4; c++) acc[a][c] += aq[a]*bq[c];
        }
        __syncthreads();
    }
    #pragma unroll
    for (int a = 0; a < 4; a++) {
        float4 o;
        o.x = leaky(acc[a][0] + b4[col0+0]);
        o.y = leaky(acc[a][1] + b4[col0+1]);
        o.z = leaky(acc[a][2] + b4[col0+2]);
        o.w = leaky(acc[a][3] + b4[col0+3]);
        *(float4*)&g2[(size_t)(row0+a)*512 + col0] = o;
    }
}

// ---------------- FC2: out = g2 @ W5[512,1024] + b5; mean | std=exp(0.5 logvar) ----------------
__global__ __launch_bounds__(256) void fc2_kernel(const float* __restrict__ g2,
                                                  const float* __restrict__ W5,
                                                  const float* __restrict__ b5,
                                                  float* __restrict__ out)
{
    int bx = blockIdx.x & 15;
    int by = blockIdx.x >> 4;
    __shared__ float AsT[16*64];
    __shared__ float Bs[16*64];
    int tid = threadIdx.x;
    int tx = tid & 15, ty = tid >> 4;
    int row0 = by*64 + ty*4, col0 = bx*64 + tx*4;
    float acc[4][4];
    #pragma unroll
    for (int a = 0; a < 4; a++)
        #pragma unroll
        for (int c = 0; c < 4; c++) acc[a][c] = 0.0f;

    for (int kb = 0; kb < 512; kb += 16) {
        for (int e = tid; e < 1024; e += 256) {
            int k = e & 15, rr = e >> 4;
            AsT[k*64 + rr] = g2[(size_t)(by*64 + rr)*512 + kb + k];
        }
        for (int e = tid; e < 1024; e += 256) {
            int cc = e & 63, k = e >> 6;
            Bs[k*64 + cc] = W5[(size_t)(kb + k)*1024 + bx*64 + cc];
        }
        __syncthreads();
        #pragma unroll
        for (int k = 0; k < 16; k++) {
            float4 av = *(const float4*)&AsT[k*64 + ty*4];
            float4 bv = *(const float4*)&Bs[k*64 + tx*4];
            float aq[4] = {av.x, av.y, av.z, av.w};
            float bq[4] = {bv.x, bv.y, bv.z, bv.w};
            #pragma unroll
            for (int a = 0; a < 4; a++)
                #pragma unroll
                for (int c = 0; c < 4; c++) acc[a][c] += aq[a]*bq[c];
        }
        __syncthreads();
    }
    #pragma unroll
    for (int a = 0; a < 4; a++) {
        int row = row0 + a;
        #pragma unroll
        for (int c = 0; c < 4; c++) {
            int col = col0 + c;
            float v = acc[a][c] + b5[col];
            if (col < 512) {
                out[MEAN_OFF + (size_t)row*512 + col] = v;
            } else {
                out[STD_OFF + (size_t)row*512 + (col - 512)] = expf(0.5f*v);
            }
        }
    }
}

extern "C" void kernel_launch(void* const* d_in, const int* in_sizes, int n_in,
                              void* d_out, int out_size, void* d_ws, size_t ws_size,
                              hipStream_t stream) {
    const float* pos = (const float*)d_in[0];
    const float* W1  = (const float*)d_in[2];
    const float* b1  = (const float*)d_in[3];
    const float* W2  = (const float*)d_in[4];
    const float* b2  = (const float*)d_in[5];
    const float* W3  = (const float*)d_in[6];
    const float* b3  = (const float*)d_in[7];
    const float* W4  = (const float*)d_in[8];
    const float* b4  = (const float*)d_in[9];
    const float* W5  = (const float*)d_in[10];
    const float* b5  = (const float*)d_in[11];
    float* out = (float*)d_out;

    char* ws = (char*)d_ws;
    float* centersWs = (float*)(ws);             // 2048*3 f32          [0, 24576)
    int*   cntWs     = (int*)(ws + 24576);       // 2048 i32
    int*   nbrWs     = (int*)(ws + 32768);       // 2048*128 i32
    float* gA        = (float*)(ws + 1081344);   // 2048*528 f32
    float* g2        = (float*)(ws + 5406720);   // 2048*512 f32        [5406720, 9601024)
    // prepped bf16 weights live inside g2's byte range (g2 written only after mlp)
    __hip_bfloat16* W2T = (__hip_bfloat16*)(ws + 9453568);   // 16 KB
    __hip_bfloat16* W3T = (__hip_bfloat16*)(ws + 9469952);   // 128 KB, ends at 9601024

    hipLaunchKernelGGL(prep_kernel, dim3(256), dim3(256), 0, stream, W2, W3, W2T, W3T);
    hipLaunchKernelGGL(fps_kernel, dim3(NB), dim3(256), 0, stream, pos, centersWs);
    hipLaunchKernelGGL(ball_kernel, dim3(NB*NS), dim3(64), 0, stream, pos, centersWs, nbrWs, cntWs, gA, out);
    hipLaunchKernelGGL(mlp_kernel, dim3(NB*NS), dim3(256), 0, stream,
                       pos, W1,b1, b2,b3, W2T, W3T, centersWs, nbrWs, cntWs, gA);
    hipLaunchKernelGGL(fc1_kernel, dim3(256), dim3(256), 0, stream, gA, W4, b4, g2);
    hipLaunchKernelGGL(fc2_kernel, dim3(512), dim3(256), 0, stream, g2, W5, b5, out);
}

// Round 4
// 180.262 us; speedup vs baseline: 4.8914x; 1.8592x over previous
//
#include <hip/hip_runtime.h>
#include <hip/hip_bf16.h>

#define NB 32
#define NP 2048
#define NS 64
#define NK 128

// d_out layout (FLOAT32 elements)
#define MEAN_OFF 0
#define STD_OFF  1048576
#define XIDX_OFF 2097152
#define YIDX_OFF 2359296

#define GA_LD 576   // gA bf16 leading dim (515 padded)

typedef __attribute__((ext_vector_type(8)))  short short8;
typedef __attribute__((ext_vector_type(16))) float f32x16;

static __device__ __forceinline__ float leaky(float x){ return x >= 0.0f ? x : 0.2f * x; }

// strict IEEE fp32, no contraction — matches numpy/jax op order
static __device__ __forceinline__ float d2s(float ax,float ay,float az,float bx,float by,float bz){
    float dx = __fsub_rn(ax,bx), dy = __fsub_rn(ay,by), dz = __fsub_rn(az,bz);
    return __fadd_rn(__fadd_rn(__fmul_rn(dx,dx),__fmul_rn(dy,dy)),__fmul_rn(dz,dz));
}

// ---------------- FPS: one block per batch ----------------
__global__ __launch_bounds__(256) void fps_kernel(const float* __restrict__ pos,
                                                  float* __restrict__ centersWs)
{
    int b = blockIdx.x;
    int t = threadIdx.x;
    __shared__ float px[NP], py[NP], pz[NP];
    __shared__ float redv[4];
    __shared__ int   redi[4];
    __shared__ int   jsh;

    const float* pb = pos + (size_t)b * NP * 3;
    for (int n = t; n < NP; n += 256) {
        px[n] = pb[n*3+0]; py[n] = pb[n*3+1]; pz[n] = pb[n*3+2];
    }
    __syncthreads();

    float p0x = px[0], p0y = py[0], p0z = pz[0];
    float dl[8];
    #pragma unroll
    for (int q = 0; q < 8; q++) {
        int n = t + q*256;
        dl[q] = d2s(px[n],py[n],pz[n], p0x,p0y,p0z);
    }
    if (t == 0) {
        centersWs[(b*NS)*3+0] = p0x;
        centersWs[(b*NS)*3+1] = p0y;
        centersWs[(b*NS)*3+2] = p0z;
    }

    for (int s = 1; s < NS; s++) {
        float bv = -1.0f; int bi = 0;
        #pragma unroll
        for (int q = 0; q < 8; q++) {
            int n = t + q*256;
            if (dl[q] > bv) { bv = dl[q]; bi = n; }
        }
        #pragma unroll
        for (int m = 32; m > 0; m >>= 1) {
            float ov = __shfl_xor(bv, m);
            int   oi = __shfl_xor(bi, m);
            if (ov > bv || (ov == bv && oi < bi)) { bv = ov; bi = oi; }
        }
        int w = t >> 6;
        if ((t & 63) == 0) { redv[w] = bv; redi[w] = bi; }
        __syncthreads();
        if (t == 0) {
            float v = redv[0]; int i = redi[0];
            #pragma unroll
            for (int k = 1; k < 4; k++) {
                if (redv[k] > v || (redv[k] == v && redi[k] < i)) { v = redv[k]; i = redi[k]; }
            }
            jsh = i;
            centersWs[(b*NS+s)*3+0] = px[i];
            centersWs[(b*NS+s)*3+1] = py[i];
            centersWs[(b*NS+s)*3+2] = pz[i];
        }
        __syncthreads();
        int j = jsh;
        float cx = px[j], cy = py[j], cz = pz[j];
        #pragma unroll
        for (int q = 0; q < 8; q++) {
            int n = t + q*256;
            dl[q] = fminf(dl[q], d2s(px[n],py[n],pz[n], cx,cy,cz));
        }
    }
}

// ---------------- ball query: one wave per center ----------------
__global__ __launch_bounds__(64) void ball_kernel(const float* __restrict__ pos,
                                                  const float* __restrict__ centersWs,
                                                  int* __restrict__ nbrWs,
                                                  int* __restrict__ cntWs,
                                                  __hip_bfloat16* __restrict__ gAb,
                                                  float* __restrict__ out)
{
    int r = blockIdx.x;        // b*NS + s
    int b = r >> 6;
    int lane = threadIdx.x;
    float cx = centersWs[r*3+0], cy = centersWs[r*3+1], cz = centersWs[r*3+2];

    __shared__ int nb[NK];
    const float* pb = pos + (size_t)b * NP * 3;
    int total = 0;
    for (int base = 0; base < NP; base += 64) {
        int n = base + lane;
        float x = pb[n*3+0], y = pb[n*3+1], z = pb[n*3+2];
        float d2 = d2s(cx,cy,cz, x,y,z);
        bool in = d2 < 0.04f;
        unsigned long long m = __ballot(in);
        int before = __popcll(m & ((1ull << lane) - 1ull));
        int p = total + before;
        if (in && p < NK) nb[p] = n;
        total += (int)__popcll(m);
        if (total >= NK) break;
    }
    int cnt = total > NK ? NK : total;
    if (lane == 0) cntWs[r] = cnt;
    __syncthreads();

    #pragma unroll
    for (int k = lane; k < NK; k += 64) {
        bool valid = k < cnt;
        int nv = valid ? nb[k] : 0;
        nbrWs[r*NK + k] = nv;
        out[XIDX_OFF + r*NK + k] = valid ? (float)(nv + b*NP) : -1.0f;
        out[YIDX_OFF + r*NK + k] = valid ? (float)r : -1.0f;
    }
    // gA tail cols 512..575: center xyz then zeros
    {
        float v = 0.0f;
        if (lane == 0) v = cx; else if (lane == 1) v = cy; else if (lane == 2) v = cz;
        gAb[(size_t)r*GA_LD + 512 + lane] = __float2bfloat16(v);
    }
}

// ---------------- prep: bf16 (transposed/swizzled) weights into ws ----------------
// W2T: [i=0..127][j=0..63] bf16, byte = i*128 + ((j*2) ^ ((i&7)<<4))    (16 KB, pre-swizzled)
// W3T: [c=0..511][i=0..127] bf16, byte = c*256 + ((i*2) ^ ((c&15)<<4)) (128 KB, pre-swizzled)
// W4T: [n=0..511][k=0..575] bf16 linear, = W4[k][n] (0 for k>=515)     (576 KB)
// W5T: [n=0..1023][k=0..511] bf16 linear, = W5[k][n]                   (1 MB)
__global__ __launch_bounds__(256) void prep_kernel(const float* __restrict__ W2,
                                                   const float* __restrict__ W3,
                                                   const float* __restrict__ W4,
                                                   const float* __restrict__ W5,
                                                   __hip_bfloat16* __restrict__ W2T,
                                                   __hip_bfloat16* __restrict__ W3T,
                                                   __hip_bfloat16* __restrict__ W4T,
                                                   __hip_bfloat16* __restrict__ W5T)
{
    int g = blockIdx.x*256 + threadIdx.x;   // 0..131071
    if (g < 65536) {
        int c = g & 511, i = g >> 9;
        float v = W3[(size_t)i*512 + c];
        int byte = c*256 + ((i*2) ^ ((c&15)<<4));
        W3T[byte>>1] = __float2bfloat16(v);
    }
    if (g < 8192) {
        int j = g >> 7, i = g & 127;
        float v = W2[(size_t)j*128 + i];
        int byte = i*128 + ((j*2) ^ ((i&7)<<4));
        W2T[byte>>1] = __float2bfloat16(v);
    }
    for (int e = g; e < 512*GA_LD; e += 131072) {
        int n = e / GA_LD, k = e - n*GA_LD;
        float v = (k < 515) ? W4[(size_t)k*512 + n] : 0.0f;
        W4T[e] = __float2bfloat16(v);
    }
    for (int e = g; e < 1024*512; e += 131072) {
        int n = e >> 9, k = e & 511;
        W5T[e] = __float2bfloat16(W5[(size_t)k*1024 + n]);
    }
}

// ---------------- fused MLP(3->64->128->512) + masked max, MFMA bf16 ----------------
__global__ __launch_bounds__(256) void mlp_kernel(const float* __restrict__ pos,
                                                  const float* __restrict__ W1, const float* __restrict__ b1,
                                                  const float* __restrict__ b2, const float* __restrict__ b3,
                                                  const __hip_bfloat16* __restrict__ W2T,
                                                  const __hip_bfloat16* __restrict__ W3T,
                                                  const float* __restrict__ centersWs,
                                                  const int* __restrict__ nbrWs,
                                                  const int* __restrict__ cntWs,
                                                  __hip_bfloat16* __restrict__ gAb)
{
    __shared__ char smem[67584];
    char* h1s = smem;                 // [0,16384)       layer1 out  [k][j] swz (k&7)<<4
    char* w2s = smem + 16384;         // [16384,32768)   W2T image
    char* w3s = smem;                 // [0,32768)       layer3 B chunk (aliases h1s+w2s)
    char* h2s = smem + 32768;         // [32768,65536)   layer2 out  [k][i] swz (k&15)<<4
    float* rel = (float*)(smem + 65536);   // 128*4 f32 (2 KB)
    float* red = (float*)(smem + 65536);   // 256 f32 (aliases rel; rel dead by layer3)

    int r = blockIdx.x, b = r >> 6, tid = threadIdx.x;
    int l = tid & 63, w = tid >> 6;
    int wr = w & 1, wc = w >> 1;
    int colsel = (l >> 5) * 16;       // byte offset of the lane's K-subgroup
    int cnt = cntWs[r];
    float cx = centersWs[r*3+0], cy = centersWs[r*3+1], cz = centersWs[r*3+2];

    #pragma unroll
    for (int it = 0; it < 4; it++) {
        int off = (it*256 + tid) * 16;
        *(short8*)(w2s + off) = *(const short8*)((const char*)W2T + off);
    }
    if (tid < NK) {
        int nv = nbrWs[r*NK + tid];
        const float* pp = pos + ((size_t)b*NP + nv)*3;
        rel[tid*4+0] = pp[0] - cx;
        rel[tid*4+1] = pp[1] - cy;
        rel[tid*4+2] = pp[2] - cz;
        rel[tid*4+3] = 0.0f;
    }
    __syncthreads();

    // ---- layer 1 (VALU)
    {
        int j = l;
        float wa = W1[j], wb = W1[64+j], wcc = W1[128+j], bb = b1[j];
        #pragma unroll
        for (int e = 0; e < 32; e++) {
            int k = e*4 + w;
            float a = bb + rel[k*4+0]*wa + rel[k*4+1]*wb + rel[k*4+2]*wcc;
            a = leaky(a);
            int byte = k*128 + ((j*2) ^ ((k&7)<<4));
            *(__hip_bfloat16*)(h1s + byte) = __float2bfloat16(a);
        }
    }
    __syncthreads();

    // ---- layer 2 (MFMA): M=128,N=128,K=64
    {
        f32x16 acc[2][2];
        #pragma unroll
        for (int q = 0; q < 16; q++) { acc[0][0][q]=0.f; acc[0][1][q]=0.f; acc[1][0][q]=0.f; acc[1][1][q]=0.f; }
        int ra0 = (2*wr)*32 + (l & 31), ra1 = ra0 + 32;
        int rb0 = (2*wc)*32 + (l & 31), rb1 = rb0 + 32;
        #pragma unroll
        for (int ks = 0; ks < 4; ks++) {
            int bc = ks*32 + colsel;
            short8 a0 = *(short8*)(h1s + ra0*128 + (bc ^ ((ra0&7)<<4)));
            short8 a1 = *(short8*)(h1s + ra1*128 + (bc ^ ((ra1&7)<<4)));
            short8 bv0 = *(short8*)(w2s + rb0*128 + (bc ^ ((rb0&7)<<4)));
            short8 bv1 = *(short8*)(w2s + rb1*128 + (bc ^ ((rb1&7)<<4)));
            acc[0][0] = __builtin_amdgcn_mfma_f32_32x32x16_bf16(a0, bv0, acc[0][0], 0, 0, 0);
            acc[0][1] = __builtin_amdgcn_mfma_f32_32x32x16_bf16(a0, bv1, acc[0][1], 0, 0, 0);
            acc[1][0] = __builtin_amdgcn_mfma_f32_32x32x16_bf16(a1, bv0, acc[1][0], 0, 0, 0);
            acc[1][1] = __builtin_amdgcn_mfma_f32_32x32x16_bf16(a1, bv1, acc[1][1], 0, 0, 0);
        }
        float bi0 = b2[rb0], bi1 = b2[rb1];
        #pragma unroll
        for (int rt = 0; rt < 2; rt++) {
            int kbase = (2*wr + rt)*32 + 4*(l>>5);
            #pragma unroll
            for (int reg = 0; reg < 16; reg++) {
                int k = kbase + (reg&3) + 8*(reg>>2);
                float v0 = leaky(acc[rt][0][reg] + bi0);
                float v1 = leaky(acc[rt][1][reg] + bi1);
                *(__hip_bfloat16*)(h2s + k*256 + ((rb0*2) ^ ((k&15)<<4))) = __float2bfloat16(v0);
                *(__hip_bfloat16*)(h2s + k*256 + ((rb1*2) ^ ((k&15)<<4))) = __float2bfloat16(v1);
            }
        }
    }
    __syncthreads();

    // ---- preload layer3 A-frags
    short8 a3[2][8];
    {
        #pragma unroll
        for (int rt = 0; rt < 2; rt++) {
            int row = (2*wr + rt)*32 + (l & 31);
            #pragma unroll
            for (int ks = 0; ks < 8; ks++) {
                int bc = ks*32 + colsel;
                a3[rt][ks] = *(short8*)(h2s + row*256 + (bc ^ ((row&15)<<4)));
            }
        }
    }

    // ---- layer 3 (MFMA) + masked max: N=512 in 4 chunks of 128
    int rb0 = (2*wc)*32 + (l & 31), rb1 = rb0 + 32;
    for (int cc = 0; cc < 4; cc++) {
        const char* src = (const char*)W3T + cc*32768;
        #pragma unroll
        for (int it = 0; it < 8; it++) {
            int off = (it*256 + tid) * 16;
            *(short8*)(w3s + off) = *(const short8*)(src + off);
        }
        __syncthreads();

        f32x16 a00, a01, a10, a11;
        #pragma unroll
        for (int q = 0; q < 16; q++) { a00[q]=0.f; a01[q]=0.f; a10[q]=0.f; a11[q]=0.f; }
        #pragma unroll
        for (int ks = 0; ks < 8; ks++) {
            int bc = ks*32 + colsel;
            short8 bv0 = *(short8*)(w3s + rb0*256 + (bc ^ ((rb0&15)<<4)));
            short8 bv1 = *(short8*)(w3s + rb1*256 + (bc ^ ((rb1&15)<<4)));
            a00 = __builtin_amdgcn_mfma_f32_32x32x16_bf16(a3[0][ks], bv0, a00, 0, 0, 0);
            a01 = __builtin_amdgcn_mfma_f32_32x32x16_bf16(a3[0][ks], bv1, a01, 0, 0, 0);
            a10 = __builtin_amdgcn_mfma_f32_32x32x16_bf16(a3[1][ks], bv0, a10, 0, 0, 0);
            a11 = __builtin_amdgcn_mfma_f32_32x32x16_bf16(a3[1][ks], bv1, a11, 0, 0, 0);
        }
        float m0 = -INFINITY, m1 = -INFINITY;
        int kb0 = 2*wr*32 + 4*(l>>5);
        #pragma unroll
        for (int reg = 0; reg < 16; reg++) {
            int kloc = (reg&3) + 8*(reg>>2);
            if (kb0 + kloc < cnt)      { m0 = fmaxf(m0, a00[reg]); m1 = fmaxf(m1, a01[reg]); }
            if (kb0 + 32 + kloc < cnt) { m0 = fmaxf(m0, a10[reg]); m1 = fmaxf(m1, a11[reg]); }
        }
        m0 = fmaxf(m0, __shfl_xor(m0, 32));
        m1 = fmaxf(m1, __shfl_xor(m1, 32));
        if (l < 32) {
            red[wr*128 + rb0] = m0;
            red[wr*128 + rb1] = m1;
        }
        __syncthreads();
        if (tid < 128) {
            float m = fmaxf(red[tid], red[128 + tid]);
            int c = cc*128 + tid;
            gAb[(size_t)r*GA_LD + c] = __float2bfloat16(leaky(m + b3[c]));
        }
        __syncthreads();
    }
}

// ---------------- FC1 (MFMA): g2b = leaky(gAb[2048,576] @ W4T' + b4), N=512 ----------------
__global__ __launch_bounds__(256) void fc1_kernel(const __hip_bfloat16* __restrict__ gAb,
                                                  const __hip_bfloat16* __restrict__ W4T,
                                                  const float* __restrict__ b4,
                                                  __hip_bfloat16* __restrict__ g2b)
{
    __shared__ char smem[16384];
    char* As = smem;            // [64 rows][64 k] bf16, swz ((row&7)<<4)
    char* Bs = smem + 8192;     // [64 cols][64 k] bf16, swz

    int bx = blockIdx.x & 7;    // N tile (512/64)
    int by = blockIdx.x >> 3;   // M tile (2048/64)
    int tid = threadIdx.x;
    int l = tid & 63, w = tid >> 6;
    int wm = w & 1, wn = w >> 1;
    int colsel = (l >> 5) * 16;

    f32x16 acc;
    #pragma unroll
    for (int q = 0; q < 16; q++) acc[q] = 0.f;

    int ra = wm*32 + (l & 31);
    int rn = wn*32 + (l & 31);

    for (int kb = 0; kb < GA_LD; kb += 64) {
        #pragma unroll
        for (int it = 0; it < 2; it++) {
            int e = it*256 + tid;            // 0..511
            int row = e >> 3, seg = e & 7;
            short8 va = *(const short8*)(gAb + (size_t)(by*64 + row)*GA_LD + kb + seg*8);
            *(short8*)(As + row*128 + ((seg*16) ^ ((row&7)<<4))) = va;
            short8 vb = *(const short8*)(W4T + (size_t)(bx*64 + row)*GA_LD + kb + seg*8);
            *(short8*)(Bs + row*128 + ((seg*16) ^ ((row&7)<<4))) = vb;
        }
        __syncthreads();
        #pragma unroll
        for (int ks = 0; ks < 4; ks++) {
            int bc = ks*32 + colsel;
            short8 av = *(short8*)(As + ra*128 + (bc ^ ((ra&7)<<4)));
            short8 bv = *(short8*)(Bs + rn*128 + (bc ^ ((rn&7)<<4)));
            acc = __builtin_amdgcn_mfma_f32_32x32x16_bf16(av, bv, acc, 0, 0, 0);
        }
        __syncthreads();
    }

    int col = bx*64 + wn*32 + (l & 31);
    float bcol = b4[col];
    int rbase = by*64 + wm*32 + 4*(l>>5);
    #pragma unroll
    for (int reg = 0; reg < 16; reg++) {
        int row = rbase + (reg&3) + 8*(reg>>2);
        g2b[(size_t)row*512 + col] = __float2bfloat16(leaky(acc[reg] + bcol));
    }
}

// ---------------- FC2 (MFMA): out = g2b @ W5T' + b5; mean | std=exp(0.5 lv) ----------------
__global__ __launch_bounds__(256) void fc2_kernel(const __hip_bfloat16* __restrict__ g2b,
                                                  const __hip_bfloat16* __restrict__ W5T,
                                                  const float* __restrict__ b5,
                                                  float* __restrict__ out)
{
    __shared__ char smem[16384];
    char* As = smem;
    char* Bs = smem + 8192;

    int bx = blockIdx.x & 15;   // N tile (1024/64)
    int by = blockIdx.x >> 4;   // M tile (2048/64)
    int tid = threadIdx.x;
    int l = tid & 63, w = tid >> 6;
    int wm = w & 1, wn = w >> 1;
    int colsel = (l >> 5) * 16;

    f32x16 acc;
    #pragma unroll
    for (int q = 0; q < 16; q++) acc[q] = 0.f;

    int ra = wm*32 + (l & 31);
    int rn = wn*32 + (l & 31);

    for (int kb = 0; kb < 512; kb += 64) {
        #pragma unroll
        for (int it = 0; it < 2; it++) {
            int e = it*256 + tid;
            int row = e >> 3, seg = e & 7;
            short8 va = *(const short8*)(g2b + (size_t)(by*64 + row)*512 + kb + seg*8);
            *(short8*)(As + row*128 + ((seg*16) ^ ((row&7)<<4))) = va;
            short8 vb = *(const short8*)(W5T + (size_t)(bx*64 + row)*512 + kb + seg*8);
            *(short8*)(Bs + row*128 + ((seg*16) ^ ((row&7)<<4))) = vb;
        }
        __syncthreads();
        #pragma unroll
        for (int ks = 0; ks < 4; ks++) {
            int bc = ks*32 + colsel;
            short8 av = *(short8*)(As + ra*128 + (bc ^ ((ra&7)<<4)));
            short8 bv = *(short8*)(Bs + rn*128 + (bc ^ ((rn&7)<<4)));
            acc = __builtin_amdgcn_mfma_f32_32x32x16_bf16(av, bv, acc, 0, 0, 0);
        }
        __syncthreads();
    }

    int col = bx*64 + wn*32 + (l & 31);
    float bcol = b5[col];
    int rbase = by*64 + wm*32 + 4*(l>>5);
    #pragma unroll
    for (int reg = 0; reg < 16; reg++) {
        int row = rbase + (reg&3) + 8*(reg>>2);
        float v = acc[reg] + bcol;
        if (col < 512) {
            out[MEAN_OFF + (size_t)row*512 + col] = v;
        } else {
            out[STD_OFF + (size_t)row*512 + (col - 512)] = expf(0.5f*v);
        }
    }
}

extern "C" void kernel_launch(void* const* d_in, const int* in_sizes, int n_in,
                              void* d_out, int out_size, void* d_ws, size_t ws_size,
                              hipStream_t stream) {
    const float* pos = (const float*)d_in[0];
    const float* W1  = (const float*)d_in[2];
    const float* b1  = (const float*)d_in[3];
    const float* W2  = (const float*)d_in[4];
    const float* b2  = (const float*)d_in[5];
    const float* W3  = (const float*)d_in[6];
    const float* b3  = (const float*)d_in[7];
    const float* W4  = (const float*)d_in[8];
    const float* b4  = (const float*)d_in[9];
    const float* W5  = (const float*)d_in[10];
    const float* b5  = (const float*)d_in[11];
    float* out = (float*)d_out;

    char* ws = (char*)d_ws;
    float* centersWs = (float*)(ws);                          // 24576 B
    int*   cntWs     = (int*)(ws + 24576);                    // 8 KB
    int*   nbrWs     = (int*)(ws + 32768);                    // 1 MB
    __hip_bfloat16* gAb = (__hip_bfloat16*)(ws + 1081344);    // 2048*576*2 = 2359296
    __hip_bfloat16* g2b = (__hip_bfloat16*)(ws + 3440640);    // 2048*512*2 = 2097152
    __hip_bfloat16* W2T = (__hip_bfloat16*)(ws + 5537792);    // 16 KB
    __hip_bfloat16* W3T = (__hip_bfloat16*)(ws + 5554176);    // 128 KB
    __hip_bfloat16* W4T = (__hip_bfloat16*)(ws + 5685248);    // 576 KB
    __hip_bfloat16* W5T = (__hip_bfloat16*)(ws + 6275072);    // 1 MB -> ends 7323648

    hipLaunchKernelGGL(prep_kernel, dim3(512), dim3(256), 0, stream, W2, W3, W4, W5, W2T, W3T, W4T, W5T);
    hipLaunchKernelGGL(fps_kernel, dim3(NB), dim3(256), 0, stream, pos, centersWs);
    hipLaunchKernelGGL(ball_kernel, dim3(NB*NS), dim3(64), 0, stream, pos, centersWs, nbrWs, cntWs, gAb, out);
    hipLaunchKernelGGL(mlp_kernel, dim3(NB*NS), dim3(256), 0, stream,
                       pos, W1,b1, b2,b3, W2T, W3T, centersWs, nbrWs, cntWs, gAb);
    hipLaunchKernelGGL(fc1_kernel, dim3(256), dim3(256), 0, stream, gAb, W4T, b4, g2b);
    hipLaunchKernelGGL(fc2_kernel, dim3(512), dim3(256), 0, stream, g2b, W5T, b5, out);
}